// Round 2
// baseline (415.179 us; speedup 1.0000x reference)
//
#include <hip/hip_runtime.h>
#include <stdint.h>
#include <type_traits>

// Problem constants
#define B_    2
#define HW_   4096
#define NTGT_ 4096
#define C_    512
#define H_    8
#define KNN_  32
#define DH_   64
#define M_    (B_ * HW_)   // 8192 rows on both src and tgt side

typedef unsigned short ushort_t;

__device__ __forceinline__ float b2f(ushort_t u) {
    union { uint32_t i; float f; } x;
    x.i = ((uint32_t)u) << 16;
    return x.f;
}
__device__ __forceinline__ ushort_t f2b(float f) {
    union { float f; uint32_t i; } x;
    x.f = f;
    uint32_t r = x.i + 0x7fffu + ((x.i >> 16) & 1u);  // round-nearest-even
    return (ushort_t)(r >> 16);
}

// Load 4 consecutive elements as float4 (bf16 or fp32 source)
template <typename T>
__device__ __forceinline__ float4 ld4(const T* p);
template <>
__device__ __forceinline__ float4 ld4<float>(const float* p) {
    return *(const float4*)p;
}
template <>
__device__ __forceinline__ float4 ld4<ushort_t>(const ushort_t* p) {
    uint2 d = *(const uint2*)p;
    return make_float4(b2f((ushort_t)(d.x & 0xffffu)), b2f((ushort_t)(d.x >> 16)),
                       b2f((ushort_t)(d.y & 0xffffu)), b2f((ushort_t)(d.y >> 16)));
}
template <typename T>
__device__ __forceinline__ float ld1(const T* p) {
    if constexpr (std::is_same<T, float>::value) return *p;
    else return b2f(*p);
}

// ---------------------------------------------------------------------------
// Tiled GEMM: O[M,512] = A[M,512] @ W[512,512] + bias.  fp32 FMA math.
// AT: A dtype, WT: W/bias dtype, OT: output dtype.
// Block 256 threads computes a 64x64 tile; BK=16.
// ---------------------------------------------------------------------------
template <typename AT, typename WT, typename OT>
__global__ __launch_bounds__(256) void gemm512(const AT* __restrict__ A,
                                               const WT* __restrict__ W,
                                               const WT* __restrict__ bias,
                                               OT* __restrict__ O) {
    __shared__ float As[16][68];  // [k][m]; 68-float stride = 272 B (16B-aligned)
    __shared__ float Bs[16][68];  // [k][n]

    const int tid = threadIdx.x;
    const int tx = tid & 15;
    const int ty = tid >> 4;
    const int bn = blockIdx.x * 64;
    const int bm = blockIdx.y * 64;

    const int ar = tid >> 2;        // 0..63 : m (A load)
    const int ac = (tid & 3) * 4;   // 0..12 : k (A load)
    const int wk = tid >> 4;        // 0..15 : k (W load)
    const int wn = (tid & 15) * 4;  // 0..60 : n (W load)

    float acc[4][4] = {};

    for (int kt = 0; kt < 512; kt += 16) {
        {
            float4 d = ld4<AT>(A + (size_t)(bm + ar) * 512 + kt + ac);
            As[ac + 0][ar] = d.x;
            As[ac + 1][ar] = d.y;
            As[ac + 2][ar] = d.z;
            As[ac + 3][ar] = d.w;
        }
        {
            float4 d = ld4<WT>(W + (size_t)(kt + wk) * 512 + bn + wn);
            Bs[wk][wn + 0] = d.x;
            Bs[wk][wn + 1] = d.y;
            Bs[wk][wn + 2] = d.z;
            Bs[wk][wn + 3] = d.w;
        }
        __syncthreads();

#pragma unroll
        for (int kk = 0; kk < 16; ++kk) {
            float4 a4 = *(const float4*)&As[kk][ty * 4];
            float4 b4 = *(const float4*)&Bs[kk][tx * 4];
            float av[4] = {a4.x, a4.y, a4.z, a4.w};
            float bv[4] = {b4.x, b4.y, b4.z, b4.w};
#pragma unroll
            for (int i = 0; i < 4; ++i)
#pragma unroll
                for (int j = 0; j < 4; ++j)
                    acc[i][j] = fmaf(av[i], bv[j], acc[i][j]);
        }
        __syncthreads();
    }

    const int col0 = bn + tx * 4;
    const int row0 = bm + ty * 4;
    float bl[4];
#pragma unroll
    for (int j = 0; j < 4; ++j) bl[j] = ld1<WT>(bias + col0 + j);

    if constexpr (std::is_same<OT, ushort_t>::value) {
#pragma unroll
        for (int i = 0; i < 4; ++i) {
            uint32_t p0 = (uint32_t)f2b(acc[i][0] + bl[0]) |
                          ((uint32_t)f2b(acc[i][1] + bl[1]) << 16);
            uint32_t p1 = (uint32_t)f2b(acc[i][2] + bl[2]) |
                          ((uint32_t)f2b(acc[i][3] + bl[3]) << 16);
            *(uint2*)&O[(size_t)(row0 + i) * 512 + col0] = make_uint2(p0, p1);
        }
    } else {
#pragma unroll
        for (int i = 0; i < 4; ++i) {
            *(float4*)&O[(size_t)(row0 + i) * 512 + col0] =
                make_float4(acc[i][0] + bl[0], acc[i][1] + bl[1],
                            acc[i][2] + bl[2], acc[i][3] + bl[3]);
        }
    }
}

// ---------------------------------------------------------------------------
// Gather attention: one block per (b, q). Q/K/V are bf16.
// Threads: (h = t>>5, n = t&31) for logits; 32-lane shuffle softmax;
// (h = t>>5, d2 = 2*(t&31)) for PV.  O aliases Q (same-row only: the block
// reads its Q row into LDS before writing the O row).
// ---------------------------------------------------------------------------
template <typename WT, typename IT>
__global__ __launch_bounds__(256) void attn_kernel(const ushort_t* Q,
                                                   const ushort_t* __restrict__ K,
                                                   const ushort_t* __restrict__ V,
                                                   const IT* __restrict__ idx,
                                                   const WT* __restrict__ wts,
                                                   ushort_t* O) {
    __shared__ float qs[512];
    __shared__ float ps[H_][KNN_];
    __shared__ int idxs[KNN_];
    __shared__ float ws[KNN_];

    const int t = threadIdx.x;
    const int bq = blockIdx.x;    // b*HW + q
    const int b = bq >> 12;       // HW = 4096
    const size_t qoff = (size_t)bq * C_;

    {   // 512 bf16 q values -> fp32 LDS (each thread unpacks one dword)
        uint32_t d = *(const uint32_t*)(Q + qoff + 2 * t);
        qs[2 * t + 0] = b2f((ushort_t)(d & 0xffffu));
        qs[2 * t + 1] = b2f((ushort_t)(d >> 16));
    }
    if (t < KNN_) {
        idxs[t] = (int)idx[(size_t)bq * KNN_ + t];
        ws[t] = ld1<WT>(wts + (size_t)bq * KNN_ + t);
    }
    __syncthreads();

    const int h = t >> 5;
    const int n = t & 31;
    const ushort_t* krow = K + ((size_t)(b * NTGT_ + idxs[n])) * C_ + h * DH_;
    const float* qh = qs + h * DH_;
    float dot = 0.f;
#pragma unroll
    for (int d0 = 0; d0 < DH_; d0 += 8) {
        uint4 kv = *(const uint4*)(krow + d0);  // 8 bf16
        dot = fmaf(qh[d0 + 0], b2f((ushort_t)(kv.x & 0xffffu)), dot);
        dot = fmaf(qh[d0 + 1], b2f((ushort_t)(kv.x >> 16)), dot);
        dot = fmaf(qh[d0 + 2], b2f((ushort_t)(kv.y & 0xffffu)), dot);
        dot = fmaf(qh[d0 + 3], b2f((ushort_t)(kv.y >> 16)), dot);
        dot = fmaf(qh[d0 + 4], b2f((ushort_t)(kv.z & 0xffffu)), dot);
        dot = fmaf(qh[d0 + 5], b2f((ushort_t)(kv.z >> 16)), dot);
        dot = fmaf(qh[d0 + 6], b2f((ushort_t)(kv.w & 0xffffu)), dot);
        dot = fmaf(qh[d0 + 7], b2f((ushort_t)(kv.w >> 16)), dot);
    }
    float logit = dot * 0.125f + ws[n];  // SCALE = DH^-0.5 = 0.125

    // softmax over n within each 32-lane group (xor<32 stays in wave half)
    float mx = logit;
#pragma unroll
    for (int o = 16; o > 0; o >>= 1) mx = fmaxf(mx, __shfl_xor(mx, o));
    float e = __expf(logit - mx);
    float s = e;
#pragma unroll
    for (int o = 16; o > 0; o >>= 1) s += __shfl_xor(s, o);
    ps[h][n] = e / s;
    __syncthreads();

    // PV: thread t -> (h, d2), one dword (2 bf16) of V per neighbor
    const int d2 = (t & 31) * 2;
    float a0 = 0.f, a1 = 0.f;
#pragma unroll 4
    for (int nn = 0; nn < KNN_; ++nn) {
        const ushort_t* vrow =
            V + ((size_t)(b * NTGT_ + idxs[nn])) * C_ + h * DH_ + d2;
        uint32_t vv = *(const uint32_t*)vrow;
        float p = ps[h][nn];
        a0 = fmaf(p, b2f((ushort_t)(vv & 0xffffu)), a0);
        a1 = fmaf(p, b2f((ushort_t)(vv >> 16)), a1);
    }
    uint32_t pk = (uint32_t)f2b(a0) | ((uint32_t)f2b(a1) << 16);
    *(uint32_t*)(O + qoff + h * DH_ + d2) = pk;
}

// ---------------------------------------------------------------------------
// Host-side dtype detection: allocation size / element count.
// Pure host query — safe under graph capture, same result every call.
// ---------------------------------------------------------------------------
static int elem_bytes(const void* p, size_t n, int dflt) {
    size_t sz = 0;
    hipError_t err = hipPointerGetAttribute(
        &sz, HIP_POINTER_ATTRIBUTE_RANGE_SIZE, (hipDeviceptr_t)(uintptr_t)p);
    if (err == hipSuccess && sz >= n && (sz % n) == 0) {
        size_t b = sz / n;
        if (b == 2 || b == 4 || b == 8) return (int)b;
    }
    return dflt;
}

extern "C" void kernel_launch(void* const* d_in, const int* in_sizes, int n_in,
                              void* d_out, int out_size, void* d_ws, size_t ws_size,
                              hipStream_t stream) {
    const void* src  = d_in[0];
    const void* tgt  = d_in[1];
    const void* idxp = d_in[2];
    const void* wtp  = d_in[3];
    const void* Wq = d_in[4];  const void* bq = d_in[5];
    const void* Wk = d_in[6];  const void* bk = d_in[7];
    const void* Wv = d_in[8];  const void* bv = d_in[9];
    const void* Wo = d_in[10]; const void* bo = d_in[11];

    const size_t NELEM = (size_t)M_ * C_;      // 4,194,304
    const size_t NIDX  = (size_t)B_ * HW_ * KNN_;  // 262,144

    const int fb = elem_bytes(src, NELEM, 2);       // float tensors: 2 (bf16) or 4 (fp32)
    const int ib = elem_bytes(idxp, NIDX, 4);       // indices: 4 (i32) or 8 (i64)
    const int ob = elem_bytes(d_out, NELEM, fb);    // output dtype follows input by default

    // Workspace layout (bf16 intermediates): Q [0,8MB) | K [8MB,16MB).
    // V lives in d_out (consumed by attn before the final GEMM overwrites it).
    // Attention output aliases Q. Total ws requirement: 16 MB.
    ushort_t* Qb = (ushort_t*)d_ws;
    ushort_t* Kb = Qb + NELEM;
    ushort_t* Vb = (ushort_t*)d_out;
    ushort_t* Ob = Qb;

    dim3 g(C_ / 64, M_ / 64);  // (8, 128)
    dim3 blk(256);
    dim3 ga(B_ * HW_);

    if (fb == 4) {
        gemm512<float, float, ushort_t><<<g, blk, 0, stream>>>(
            (const float*)src, (const float*)Wq, (const float*)bq, Qb);
        gemm512<float, float, ushort_t><<<g, blk, 0, stream>>>(
            (const float*)tgt, (const float*)Wk, (const float*)bk, Kb);
        gemm512<float, float, ushort_t><<<g, blk, 0, stream>>>(
            (const float*)tgt, (const float*)Wv, (const float*)bv, Vb);
        if (ib == 8)
            attn_kernel<float, long long><<<ga, blk, 0, stream>>>(
                Qb, Kb, Vb, (const long long*)idxp, (const float*)wtp, Ob);
        else
            attn_kernel<float, int><<<ga, blk, 0, stream>>>(
                Qb, Kb, Vb, (const int*)idxp, (const float*)wtp, Ob);
        if (ob == 4)
            gemm512<ushort_t, float, float><<<g, blk, 0, stream>>>(
                Ob, (const float*)Wo, (const float*)bo, (float*)d_out);
        else
            gemm512<ushort_t, float, ushort_t><<<g, blk, 0, stream>>>(
                Ob, (const float*)Wo, (const float*)bo, (ushort_t*)d_out);
    } else {
        gemm512<ushort_t, ushort_t, ushort_t><<<g, blk, 0, stream>>>(
            (const ushort_t*)src, (const ushort_t*)Wq, (const ushort_t*)bq, Qb);
        gemm512<ushort_t, ushort_t, ushort_t><<<g, blk, 0, stream>>>(
            (const ushort_t*)tgt, (const ushort_t*)Wk, (const ushort_t*)bk, Kb);
        gemm512<ushort_t, ushort_t, ushort_t><<<g, blk, 0, stream>>>(
            (const ushort_t*)tgt, (const ushort_t*)Wv, (const ushort_t*)bv, Vb);
        if (ib == 8)
            attn_kernel<ushort_t, long long><<<ga, blk, 0, stream>>>(
                Qb, Kb, Vb, (const long long*)idxp, (const ushort_t*)wtp, Ob);
        else
            attn_kernel<ushort_t, int><<<ga, blk, 0, stream>>>(
                Qb, Kb, Vb, (const int*)idxp, (const ushort_t*)wtp, Ob);
        if (ob == 4)
            gemm512<ushort_t, ushort_t, float><<<g, blk, 0, stream>>>(
                Ob, (const ushort_t*)Wo, (const ushort_t*)bo, (float*)d_out);
        else
            gemm512<ushort_t, ushort_t, ushort_t><<<g, blk, 0, stream>>>(
                Ob, (const ushort_t*)Wo, (const ushort_t*)bo, (ushort_t*)d_out);
    }
}

// Round 3
// 409.290 us; speedup vs baseline: 1.0144x; 1.0144x over previous
//
#include <hip/hip_runtime.h>
#include <stdint.h>
#include <type_traits>

// Problem constants
#define B_    2
#define HW_   4096
#define NTGT_ 4096
#define C_    512
#define H_    8
#define KNN_  32
#define DH_   64
#define M_    (B_ * HW_)   // 8192 rows on both src and tgt side

typedef unsigned short ushort_t;
typedef __bf16 bf16x8 __attribute__((ext_vector_type(8)));
typedef float floatx4 __attribute__((ext_vector_type(4)));

__device__ __forceinline__ float b2f(ushort_t u) {
    union { uint32_t i; float f; } x;
    x.i = ((uint32_t)u) << 16;
    return x.f;
}
__device__ __forceinline__ ushort_t f2b(float f) {
    union { float f; uint32_t i; } x;
    x.f = f;
    uint32_t r = x.i + 0x7fffu + ((x.i >> 16) & 1u);  // round-nearest-even
    return (ushort_t)(r >> 16);
}

template <typename T>
__device__ __forceinline__ float4 ld4(const T* p);
template <>
__device__ __forceinline__ float4 ld4<float>(const float* p) {
    return *(const float4*)p;
}
template <>
__device__ __forceinline__ float4 ld4<ushort_t>(const ushort_t* p) {
    uint2 d = *(const uint2*)p;
    return make_float4(b2f((ushort_t)(d.x & 0xffffu)), b2f((ushort_t)(d.x >> 16)),
                       b2f((ushort_t)(d.y & 0xffffu)), b2f((ushort_t)(d.y >> 16)));
}
template <typename T>
__device__ __forceinline__ float ld1(const T* p) {
    if constexpr (std::is_same<T, float>::value) return *p;
    else return b2f(*p);
}

// ---------------------------------------------------------------------------
// Weight transpose (bf16): Wt[n][k] = W[k][n] for 4 512x512 matrices.
// Block = 32x32 tile via LDS; grid (16,16,4).
// ---------------------------------------------------------------------------
__global__ __launch_bounds__(256) void transpose4(
    const ushort_t* __restrict__ W0, const ushort_t* __restrict__ W1,
    const ushort_t* __restrict__ W2, const ushort_t* __restrict__ W3,
    ushort_t* __restrict__ T0, ushort_t* __restrict__ T1,
    ushort_t* __restrict__ T2, ushort_t* __restrict__ T3) {
    __shared__ ushort_t tile[32][36];  // +4 pad breaks write-phase conflicts

    const ushort_t* W = (blockIdx.z == 0) ? W0 : (blockIdx.z == 1) ? W1
                        : (blockIdx.z == 2) ? W2 : W3;
    ushort_t* T = (blockIdx.z == 0) ? T0 : (blockIdx.z == 1) ? T1
                  : (blockIdx.z == 2) ? T2 : T3;

    const int k0 = blockIdx.x * 32;
    const int n0 = blockIdx.y * 32;
    const int t = threadIdx.x;
    const int lr = t >> 3;          // 0..31
    const int lc = (t & 7) * 4;     // 0..28

    uint2 d = *(const uint2*)&W[(size_t)(k0 + lr) * 512 + n0 + lc];
    tile[lr][lc + 0] = (ushort_t)(d.x & 0xffffu);
    tile[lr][lc + 1] = (ushort_t)(d.x >> 16);
    tile[lr][lc + 2] = (ushort_t)(d.y & 0xffffu);
    tile[lr][lc + 3] = (ushort_t)(d.y >> 16);
    __syncthreads();

    uint32_t p0 = (uint32_t)tile[lc + 0][lr] | ((uint32_t)tile[lc + 1][lr] << 16);
    uint32_t p1 = (uint32_t)tile[lc + 2][lr] | ((uint32_t)tile[lc + 3][lr] << 16);
    *(uint2*)&T[(size_t)(n0 + lr) * 512 + k0 + lc] = make_uint2(p0, p1);
}

// ---------------------------------------------------------------------------
// MFMA GEMM: O[M,512] = A[M,512] @ W + bias, with Wt[n][k] = W[k][n] given.
// A bf16, Wt bf16, O = OT (bf16 or fp32). Block 256 thr = 4 waves; tile
// 128(M)x128(N); BK=32; each wave: 4x4 grid of 16x16x32 MFMAs.
// LDS padded to stride 40 elems (80 B): 2-way bank aliasing only (free).
// ---------------------------------------------------------------------------
template <typename OT>
__global__ __launch_bounds__(256) void gemm_mfma(const ushort_t* __restrict__ A,
                                                 const ushort_t* __restrict__ Wt,
                                                 const ushort_t* __restrict__ bias,
                                                 OT* __restrict__ O) {
    __shared__ ushort_t As[128][40];  // [m][k], 80 B row stride (16B-aligned)
    __shared__ ushort_t Bs[128][40];  // [n][k]

    const int t = threadIdx.x;
    const int bn = blockIdx.x * 128;
    const int bm = blockIdx.y * 128;

    const int lr = t >> 2;        // 0..63 row (load)
    const int lc = (t & 3) * 8;   // 0..24 k (load), 8 bf16 per uint4
    const int lane = t & 63;
    const int wv = t >> 6;
    const int wr = (wv >> 1) * 64;  // wave m-offset in tile
    const int wc = (wv & 1) * 64;   // wave n-offset in tile
    const int r16 = lane & 15;
    const int quad = lane >> 4;

    floatx4 acc[4][4] = {};

    for (int kt = 0; kt < 512; kt += 32) {
        // global prefetch into regs (2 uint4 for A, 2 for B)
        uint4 a0 = *(const uint4*)&A[(size_t)(bm + lr) * 512 + kt + lc];
        uint4 a1 = *(const uint4*)&A[(size_t)(bm + lr + 64) * 512 + kt + lc];
        uint4 b0 = *(const uint4*)&Wt[(size_t)(bn + lr) * 512 + kt + lc];
        uint4 b1 = *(const uint4*)&Wt[(size_t)(bn + lr + 64) * 512 + kt + lc];
        __syncthreads();  // previous iter's frag reads complete
        *(uint4*)&As[lr][lc] = a0;
        *(uint4*)&As[lr + 64][lc] = a1;
        *(uint4*)&Bs[lr][lc] = b0;
        *(uint4*)&Bs[lr + 64][lc] = b1;
        __syncthreads();

        bf16x8 af[4], bf[4];
#pragma unroll
        for (int i = 0; i < 4; ++i)
            af[i] = *(const bf16x8*)&As[wr + i * 16 + r16][quad * 8];
#pragma unroll
        for (int j = 0; j < 4; ++j)
            bf[j] = *(const bf16x8*)&Bs[wc + j * 16 + r16][quad * 8];
#pragma unroll
        for (int i = 0; i < 4; ++i)
#pragma unroll
            for (int j = 0; j < 4; ++j)
                acc[i][j] = __builtin_amdgcn_mfma_f32_16x16x32_bf16(
                    af[i], bf[j], acc[i][j], 0, 0, 0);
    }

    // Epilogue: C/D layout col=lane&15, row=quad*4+reg  [m89-verified]
#pragma unroll
    for (int j = 0; j < 4; ++j) {
        const int col = bn + wc + j * 16 + r16;
        const float bj = b2f(bias[col]);
#pragma unroll
        for (int i = 0; i < 4; ++i) {
            const int row = bm + wr + i * 16 + quad * 4;
#pragma unroll
            for (int r = 0; r < 4; ++r) {
                float v = acc[i][j][r] + bj;
                if constexpr (std::is_same<OT, ushort_t>::value)
                    O[(size_t)(row + r) * 512 + col] = f2b(v);
                else
                    O[(size_t)(row + r) * 512 + col] = v;
            }
        }
    }
}

// ---------------------------------------------------------------------------
// fp32-fallback tiled GEMM (kept from R2; only used if inputs are fp32)
// ---------------------------------------------------------------------------
template <typename AT, typename WT, typename OT>
__global__ __launch_bounds__(256) void gemm512(const AT* __restrict__ A,
                                               const WT* __restrict__ W,
                                               const WT* __restrict__ bias,
                                               OT* __restrict__ O) {
    __shared__ float As[16][68];
    __shared__ float Bs[16][68];

    const int tid = threadIdx.x;
    const int tx = tid & 15;
    const int ty = tid >> 4;
    const int bn = blockIdx.x * 64;
    const int bm = blockIdx.y * 64;

    const int ar = tid >> 2;
    const int ac = (tid & 3) * 4;
    const int wk = tid >> 4;
    const int wn = (tid & 15) * 4;

    float acc[4][4] = {};

    for (int kt = 0; kt < 512; kt += 16) {
        {
            float4 d = ld4<AT>(A + (size_t)(bm + ar) * 512 + kt + ac);
            As[ac + 0][ar] = d.x; As[ac + 1][ar] = d.y;
            As[ac + 2][ar] = d.z; As[ac + 3][ar] = d.w;
        }
        {
            float4 d = ld4<WT>(W + (size_t)(kt + wk) * 512 + bn + wn);
            Bs[wk][wn + 0] = d.x; Bs[wk][wn + 1] = d.y;
            Bs[wk][wn + 2] = d.z; Bs[wk][wn + 3] = d.w;
        }
        __syncthreads();
#pragma unroll
        for (int kk = 0; kk < 16; ++kk) {
            float4 a4 = *(const float4*)&As[kk][ty * 4];
            float4 b4 = *(const float4*)&Bs[kk][tx * 4];
            float av[4] = {a4.x, a4.y, a4.z, a4.w};
            float bv[4] = {b4.x, b4.y, b4.z, b4.w};
#pragma unroll
            for (int i = 0; i < 4; ++i)
#pragma unroll
                for (int j = 0; j < 4; ++j)
                    acc[i][j] = fmaf(av[i], bv[j], acc[i][j]);
        }
        __syncthreads();
    }

    const int col0 = bn + tx * 4;
    const int row0 = bm + ty * 4;
    float bl[4];
#pragma unroll
    for (int j = 0; j < 4; ++j) bl[j] = ld1<WT>(bias + col0 + j);

    if constexpr (std::is_same<OT, ushort_t>::value) {
#pragma unroll
        for (int i = 0; i < 4; ++i) {
            uint32_t p0 = (uint32_t)f2b(acc[i][0] + bl[0]) |
                          ((uint32_t)f2b(acc[i][1] + bl[1]) << 16);
            uint32_t p1 = (uint32_t)f2b(acc[i][2] + bl[2]) |
                          ((uint32_t)f2b(acc[i][3] + bl[3]) << 16);
            *(uint2*)&O[(size_t)(row0 + i) * 512 + col0] = make_uint2(p0, p1);
        }
    } else {
#pragma unroll
        for (int i = 0; i < 4; ++i) {
            *(float4*)&O[(size_t)(row0 + i) * 512 + col0] =
                make_float4(acc[i][0] + bl[0], acc[i][1] + bl[1],
                            acc[i][2] + bl[2], acc[i][3] + bl[3]);
        }
    }
}

// ---------------------------------------------------------------------------
// Gather attention: one block per (b, q). Q/K/V bf16.
// (h = t>>5, n = t&31) for logits; 32-lane shuffle softmax;
// (h = t>>5, d2 = 2*(t&31)) for PV.  O aliases Q (same-row only).
// ---------------------------------------------------------------------------
template <typename WT, typename IT>
__global__ __launch_bounds__(256) void attn_kernel(const ushort_t* Q,
                                                   const ushort_t* __restrict__ K,
                                                   const ushort_t* __restrict__ V,
                                                   const IT* __restrict__ idx,
                                                   const WT* __restrict__ wts,
                                                   ushort_t* O) {
    __shared__ float qs[512];
    __shared__ float ps[H_][KNN_];
    __shared__ int idxs[KNN_];
    __shared__ float ws[KNN_];

    const int t = threadIdx.x;
    const int bq = blockIdx.x;
    const int b = bq >> 12;
    const size_t qoff = (size_t)bq * C_;

    {
        uint32_t d = *(const uint32_t*)(Q + qoff + 2 * t);
        qs[2 * t + 0] = b2f((ushort_t)(d & 0xffffu));
        qs[2 * t + 1] = b2f((ushort_t)(d >> 16));
    }
    if (t < KNN_) {
        idxs[t] = (int)idx[(size_t)bq * KNN_ + t];
        ws[t] = ld1<WT>(wts + (size_t)bq * KNN_ + t);
    }
    __syncthreads();

    const int h = t >> 5;
    const int n = t & 31;
    const ushort_t* krow = K + ((size_t)(b * NTGT_ + idxs[n])) * C_ + h * DH_;
    const float* qh = qs + h * DH_;
    float dot = 0.f;
#pragma unroll
    for (int d0 = 0; d0 < DH_; d0 += 8) {
        uint4 kv = *(const uint4*)(krow + d0);
        dot = fmaf(qh[d0 + 0], b2f((ushort_t)(kv.x & 0xffffu)), dot);
        dot = fmaf(qh[d0 + 1], b2f((ushort_t)(kv.x >> 16)), dot);
        dot = fmaf(qh[d0 + 2], b2f((ushort_t)(kv.y & 0xffffu)), dot);
        dot = fmaf(qh[d0 + 3], b2f((ushort_t)(kv.y >> 16)), dot);
        dot = fmaf(qh[d0 + 4], b2f((ushort_t)(kv.z & 0xffffu)), dot);
        dot = fmaf(qh[d0 + 5], b2f((ushort_t)(kv.z >> 16)), dot);
        dot = fmaf(qh[d0 + 6], b2f((ushort_t)(kv.w & 0xffffu)), dot);
        dot = fmaf(qh[d0 + 7], b2f((ushort_t)(kv.w >> 16)), dot);
    }
    float logit = dot * 0.125f + ws[n];

    float mx = logit;
#pragma unroll
    for (int o = 16; o > 0; o >>= 1) mx = fmaxf(mx, __shfl_xor(mx, o));
    float e = __expf(logit - mx);
    float s = e;
#pragma unroll
    for (int o = 16; o > 0; o >>= 1) s += __shfl_xor(s, o);
    ps[h][n] = e / s;
    __syncthreads();

    const int d2 = (t & 31) * 2;
    float a0 = 0.f, a1 = 0.f;
#pragma unroll 4
    for (int nn = 0; nn < KNN_; ++nn) {
        const ushort_t* vrow =
            V + ((size_t)(b * NTGT_ + idxs[nn])) * C_ + h * DH_ + d2;
        uint32_t vv = *(const uint32_t*)vrow;
        float p = ps[h][nn];
        a0 = fmaf(p, b2f((ushort_t)(vv & 0xffffu)), a0);
        a1 = fmaf(p, b2f((ushort_t)(vv >> 16)), a1);
    }
    uint32_t pk = (uint32_t)f2b(a0) | ((uint32_t)f2b(a1) << 16);
    *(uint32_t*)(O + qoff + h * DH_ + d2) = pk;
}

// ---------------------------------------------------------------------------
static int elem_bytes(const void* p, size_t n, int dflt) {
    size_t sz = 0;
    hipError_t err = hipPointerGetAttribute(
        &sz, HIP_POINTER_ATTRIBUTE_RANGE_SIZE, (hipDeviceptr_t)(uintptr_t)p);
    if (err == hipSuccess && sz >= n && (sz % n) == 0) {
        size_t b = sz / n;
        if (b == 2 || b == 4 || b == 8) return (int)b;
    }
    return dflt;
}

extern "C" void kernel_launch(void* const* d_in, const int* in_sizes, int n_in,
                              void* d_out, int out_size, void* d_ws, size_t ws_size,
                              hipStream_t stream) {
    const void* src  = d_in[0];
    const void* tgt  = d_in[1];
    const void* idxp = d_in[2];
    const void* wtp  = d_in[3];
    const void* Wq = d_in[4];  const void* bq = d_in[5];
    const void* Wk = d_in[6];  const void* bk = d_in[7];
    const void* Wv = d_in[8];  const void* bv = d_in[9];
    const void* Wo = d_in[10]; const void* bo = d_in[11];

    const size_t NELEM = (size_t)M_ * C_;          // 4,194,304
    const size_t NIDX  = (size_t)B_ * HW_ * KNN_;  // 262,144
    const size_t WELEM = (size_t)C_ * C_;          // 262,144

    const int fb = elem_bytes(src, NELEM, 2);
    const int ib = elem_bytes(idxp, NIDX, 4);
    const int ob = elem_bytes(d_out, NELEM, fb);

    dim3 blk(256);
    dim3 ga(B_ * HW_);

    const size_t ws_need = (2 * NELEM + 4 * WELEM) * sizeof(ushort_t);  // 18.9 MB

    if (fb == 2 && ws_size >= ws_need) {
        // ---- MFMA path (bf16 inputs) ----
        // ws: Q (8MB) | K (8MB) | WtQ | WtK | WtV | WtO (0.5MB each)
        // V lives in d_out (consumed before final GEMM overwrites it);
        // attention output aliases Q.
        ushort_t* Qb  = (ushort_t*)d_ws;
        ushort_t* Kb  = Qb + NELEM;
        ushort_t* WtQ = Kb + NELEM;
        ushort_t* WtK = WtQ + WELEM;
        ushort_t* WtV = WtK + WELEM;
        ushort_t* WtO = WtV + WELEM;
        ushort_t* Vb  = (ushort_t*)d_out;
        ushort_t* Ob  = Qb;

        transpose4<<<dim3(16, 16, 4), blk, 0, stream>>>(
            (const ushort_t*)Wq, (const ushort_t*)Wk,
            (const ushort_t*)Wv, (const ushort_t*)Wo, WtQ, WtK, WtV, WtO);

        dim3 g(C_ / 128, M_ / 128);  // (4, 64) = 256 blocks
        gemm_mfma<ushort_t><<<g, blk, 0, stream>>>(
            (const ushort_t*)src, WtQ, (const ushort_t*)bq, Qb);
        gemm_mfma<ushort_t><<<g, blk, 0, stream>>>(
            (const ushort_t*)tgt, WtK, (const ushort_t*)bk, Kb);
        gemm_mfma<ushort_t><<<g, blk, 0, stream>>>(
            (const ushort_t*)tgt, WtV, (const ushort_t*)bv, Vb);

        if (ib == 8)
            attn_kernel<ushort_t, long long><<<ga, blk, 0, stream>>>(
                Qb, Kb, Vb, (const long long*)idxp, (const ushort_t*)wtp, Ob);
        else
            attn_kernel<ushort_t, int><<<ga, blk, 0, stream>>>(
                Qb, Kb, Vb, (const int*)idxp, (const ushort_t*)wtp, Ob);

        if (ob == 4)
            gemm_mfma<float><<<g, blk, 0, stream>>>(
                Ob, WtO, (const ushort_t*)bo, (float*)d_out);
        else
            gemm_mfma<ushort_t><<<g, blk, 0, stream>>>(
                Ob, WtO, (const ushort_t*)bo, (ushort_t*)d_out);
    } else if (fb == 4) {
        // ---- fp32 fallback (vector-ALU GEMMs) ----
        ushort_t* Qb = (ushort_t*)d_ws;
        ushort_t* Kb = Qb + NELEM;
        ushort_t* Vb = (ushort_t*)d_out;
        ushort_t* Ob = Qb;
        dim3 g(C_ / 64, M_ / 64);

        gemm512<float, float, ushort_t><<<g, blk, 0, stream>>>(
            (const float*)src, (const float*)Wq, (const float*)bq, Qb);
        gemm512<float, float, ushort_t><<<g, blk, 0, stream>>>(
            (const float*)tgt, (const float*)Wk, (const float*)bk, Kb);
        gemm512<float, float, ushort_t><<<g, blk, 0, stream>>>(
            (const float*)tgt, (const float*)Wv, (const float*)bv, Vb);
        if (ib == 8)
            attn_kernel<float, long long><<<ga, blk, 0, stream>>>(
                Qb, Kb, Vb, (const long long*)idxp, (const float*)wtp, Ob);
        else
            attn_kernel<float, int><<<ga, blk, 0, stream>>>(
                Qb, Kb, Vb, (const int*)idxp, (const float*)wtp, Ob);
        if (ob == 4)
            gemm512<ushort_t, float, float><<<g, blk, 0, stream>>>(
                Ob, (const float*)Wo, (const float*)bo, (float*)d_out);
        else
            gemm512<ushort_t, float, ushort_t><<<g, blk, 0, stream>>>(
                Ob, (const float*)Wo, (const float*)bo, (ushort_t*)d_out);
    } else {
        // ---- bf16 fallback without enough ws (vector-ALU GEMMs) ----
        ushort_t* Qb = (ushort_t*)d_ws;
        ushort_t* Kb = Qb + NELEM;
        ushort_t* Vb = (ushort_t*)d_out;
        ushort_t* Ob = Qb;
        dim3 g(C_ / 64, M_ / 64);

        gemm512<ushort_t, ushort_t, ushort_t><<<g, blk, 0, stream>>>(
            (const ushort_t*)src, (const ushort_t*)Wq, (const ushort_t*)bq, Qb);
        gemm512<ushort_t, ushort_t, ushort_t><<<g, blk, 0, stream>>>(
            (const ushort_t*)tgt, (const ushort_t*)Wk, (const ushort_t*)bk, Kb);
        gemm512<ushort_t, ushort_t, ushort_t><<<g, blk, 0, stream>>>(
            (const ushort_t*)tgt, (const ushort_t*)Wv, (const ushort_t*)bv, Vb);
        if (ib == 8)
            attn_kernel<ushort_t, long long><<<ga, blk, 0, stream>>>(
                Qb, Kb, Vb, (const long long*)idxp, (const ushort_t*)wtp, Ob);
        else
            attn_kernel<ushort_t, int><<<ga, blk, 0, stream>>>(
                Qb, Kb, Vb, (const int*)idxp, (const ushort_t*)wtp, Ob);
        if (ob == 4)
            gemm512<ushort_t, ushort_t, float><<<g, blk, 0, stream>>>(
                Ob, (const ushort_t*)Wo, (const ushort_t*)bo, (float*)d_out);
        else
            gemm512<ushort_t, ushort_t, ushort_t><<<g, blk, 0, stream>>>(
                Ob, (const ushort_t*)Wo, (const ushort_t*)bo, (ushort_t*)d_out);
    }
}